// Round 2
// baseline (65.015 us; speedup 1.0000x reference)
//
#include <hip/hip_runtime.h>

// YOLOv1 loss on MI355X. Shapes: input/target (4096, 14, 14, 30) f32.
// Output: scalar f32 = total_loss / 4096.
// Memory-bound streaming reduction (~192.7 MB read once, partially L3-resident).
//
// Round 2: drop LDS staging (it capped occupancy at 2 blocks/CU and left the
// memory pipe latency-bound at 16% HBM BW). Direct per-thread float2 loads:
// cell stride is 120 B (8 B aligned), every byte a wave touches is consumed,
// so coalescing efficiency is unchanged while TLP roughly triples.

#define COORD 5.0f
#define NOOBJ 0.5f
#define THREADS 256

__global__ __launch_bounds__(THREADS) void yolo_loss_kernel(
    const float* __restrict__ inp,
    const float* __restrict__ tgt,
    float* __restrict__ out,
    float inv_n)
{
    __shared__ float wsum[THREADS / 64];

    const int cell = blockIdx.x * THREADS + threadIdx.x;   // grid covers exactly
    const float2* ia = (const float2*)inp + (size_t)cell * 15;
    const float2* ta = (const float2*)tgt + (size_t)cell * 15;

    float ipv[30], tpv[30];
#pragma unroll
    for (int k = 0; k < 15; ++k) {
        float2 v = ia[k];
        float2 w = ta[k];
        ipv[2 * k]     = v.x;
        ipv[2 * k + 1] = v.y;
        tpv[2 * k]     = w.x;
        tpv[2 * k + 1] = w.y;
    }

    // ---- per-cell loss ----
    bool obj0 = (tpv[0] == 1.0f);
    bool obj1 = (tpv[1] == 1.0f);
    float f0 = obj0 ? 1.0f : 0.0f;                 // first == slot0 if obj0
    float f1 = (obj1 && !obj0) ? 1.0f : 0.0f;      // slot1 only if !obj0
    float hasf = (obj0 || obj1) ? 1.0f : 0.0f;

    float d0 = ipv[0] - tpv[0];
    float d1 = ipv[1] - tpv[1];
    float sqc0 = d0 * d0;
    float sqc1 = d1 * d1;

    float dx0 = ipv[2] - tpv[2], dy0 = ipv[3] - tpv[3];
    float xy0 = dx0 * dx0 + dy0 * dy0;
    float dw0 = sqrtf(ipv[4]) - sqrtf(tpv[4]);
    float dh0 = sqrtf(ipv[5]) - sqrtf(tpv[5]);
    float wh0 = dw0 * dw0 + dh0 * dh0;

    float dx1 = ipv[6] - tpv[6], dy1 = ipv[7] - tpv[7];
    float xy1 = dx1 * dx1 + dy1 * dy1;
    float dw1 = sqrtf(ipv[8]) - sqrtf(tpv[8]);
    float dh1 = sqrtf(ipv[9]) - sqrtf(tpv[9]);
    float wh1 = dw1 * dw1 + dh1 * dh1;

    float cls = 0.0f;
#pragma unroll
    for (int k = 10; k < 30; ++k) {
        float d = ipv[k] - tpv[k];
        cls = fmaf(d, d, cls);
    }

    float contrib =
        COORD * (f0 * (xy0 + wh0) + f1 * (xy1 + wh1)) +
        (f0 * sqc0 + f1 * sqc1) +
        hasf * cls +
        (1.0f - hasf) * NOOBJ * (sqc0 + sqc1);

    // ---- wave reduce (64 lanes) ----
#pragma unroll
    for (int off = 32; off > 0; off >>= 1)
        contrib += __shfl_down(contrib, off, 64);

    const int wid = threadIdx.x >> 6;
    const int lane = threadIdx.x & 63;
    if (lane == 0) wsum[wid] = contrib;
    __syncthreads();

    if (threadIdx.x == 0) {
        float s = wsum[0] + wsum[1] + wsum[2] + wsum[3];
        atomicAdd(out, s * inv_n);
    }
}

extern "C" void kernel_launch(void* const* d_in, const int* in_sizes, int n_in,
                              void* d_out, int out_size, void* d_ws, size_t ws_size,
                              hipStream_t stream) {
    const float* inp = (const float*)d_in[0];
    const float* tgt = (const float*)d_in[1];
    float* out = (float*)d_out;

    const int total_cells = 4096 * 14 * 14;        // 802816
    const int grid = total_cells / THREADS;        // 3136 exactly

    hipMemsetAsync(out, 0, sizeof(float), stream);
    yolo_loss_kernel<<<grid, THREADS, 0, stream>>>(inp, tgt, out, 1.0f / 4096.0f);
}

// Round 3
// 42.406 us; speedup vs baseline: 1.5331x; 1.5331x over previous
//
#include <hip/hip_runtime.h>

// YOLOv1 loss, MI355X. input/target (4096,14,14,30) f32 -> scalar f32 (loss/4096).
// Streaming reduction, 192.7 MB read once. Round 3: per-wave async double-buffered
// pipeline: global_load_lds (16B) staging, counted vmcnt(30), zero barriers
// (64-thread blocks = 1 wave, self-contained). Each thread computes 2 cells
// (240 B = 15 float4 per tensor) from LDS with compile-time channel layout.

#define COORD 5.0f
#define NOOBJ 0.5f

#define NCELLS   (4096 * 14 * 14)   // 802816
#define CPC      128                // cells per chunk (per wave)
#define CHB      (CPC * 120)        // 15360 B per tensor per chunk
#define NCHUNKS  (NCELLS / CPC)     // 6272
#define GRID     512                // 1 wave/block; LDS 60KB -> 2 blocks/CU

__device__ __forceinline__ float d2f(float a, float b) { float d = a - b; return d * d; }
__device__ __forceinline__ float sqd(float a, float b) {
    // (sqrt(a)-sqrt(b))^2 = a + b - 2*sqrt(a*b);  a,b >= 0
    return a + b - 2.0f * sqrtf(a * b);
}

__global__ __launch_bounds__(64) void yolo_loss_kernel(
    const float* __restrict__ inp,
    const float* __restrict__ tgt,
    float* __restrict__ out,
    float inv_n)
{
    __shared__ __align__(16) char smem[2][2][CHB];   // [dbuf][tensor][bytes] = 61440 B
    const int lane = threadIdx.x;

    const char* gi0 = (const char*)inp + (size_t)lane * 16;
    const char* gt0 = (const char*)tgt + (size_t)lane * 16;

    // issue 30 global_load_lds (15 per tensor) for chunk c into buffer b
    auto stage = [&](int b, int c) {
        const char* gi = gi0 + (size_t)c * CHB;
        const char* gt = gt0 + (size_t)c * CHB;
        char* li = &smem[b][0][0];
        char* lt = &smem[b][1][0];
#pragma unroll
        for (int k = 0; k < 15; ++k) {
            __builtin_amdgcn_global_load_lds(
                (const __attribute__((address_space(1))) void*)(gi + k * 1024),
                (__attribute__((address_space(3))) void*)(li + k * 1024), 16, 0, 0);
            __builtin_amdgcn_global_load_lds(
                (const __attribute__((address_space(1))) void*)(gt + k * 1024),
                (__attribute__((address_space(3))) void*)(lt + k * 1024), 16, 0, 0);
        }
    };

    float acc = 0.0f;
    int c = blockIdx.x;          // GRID=512 <= NCHUNKS, always valid
    stage(0, c);
    int buf = 0;

    for (; c < NCHUNKS; c += GRID) {
        const int cn = c + GRID;
        if (cn < NCHUNKS) {
            stage(buf ^ 1, cn);
            asm volatile("s_waitcnt vmcnt(30)" ::: "memory");   // current chunk landed
        } else {
            asm volatile("s_waitcnt vmcnt(0)" ::: "memory");
        }

        const float4* ia = (const float4*)(&smem[buf][0][0] + lane * 240);
        const float4* ta = (const float4*)(&smem[buf][1][0] + lane * 240);

        float4 I0 = ia[0],  T0 = ta[0];    // A: conf0 conf1 x0 y0
        float4 I1 = ia[1],  T1 = ta[1];    // A: w0 h0 x1 y1
        float4 I2 = ia[2],  T2 = ta[2];    // A: w1 h1 cls0 cls1
        float4 I3 = ia[3],  T3 = ta[3];    // A cls
        float4 I4 = ia[4],  T4 = ta[4];    // A cls
        float4 I5 = ia[5],  T5 = ta[5];    // A cls
        float4 I6 = ia[6],  T6 = ta[6];    // A cls
        float4 I7 = ia[7],  T7 = ta[7];    // A cls18 cls19 | B conf0 conf1
        float4 I8 = ia[8],  T8 = ta[8];    // B: x0 y0 w0 h0
        float4 I9 = ia[9],  T9 = ta[9];    // B: x1 y1 w1 h1
        float4 I10 = ia[10], T10 = ta[10]; // B cls
        float4 I11 = ia[11], T11 = ta[11];
        float4 I12 = ia[12], T12 = ta[12];
        float4 I13 = ia[13], T13 = ta[13];
        float4 I14 = ia[14], T14 = ta[14];

        // ---- cell A ----
        {
            bool o0 = (T0.x == 1.0f), o1 = (T0.y == 1.0f);
            float f0 = o0 ? 1.0f : 0.0f;
            float f1 = (o1 && !o0) ? 1.0f : 0.0f;
            float nf = (o0 || o1) ? 0.0f : 1.0f;        // 1 - has_obj
            float h  = 1.0f - nf;
            float s0 = d2f(I0.x, T0.x), s1 = d2f(I0.y, T0.y);
            float xy0 = d2f(I0.z, T0.z) + d2f(I0.w, T0.w);
            float wh0 = sqd(I1.x, T1.x) + sqd(I1.y, T1.y);
            float xy1 = d2f(I1.z, T1.z) + d2f(I1.w, T1.w);
            float wh1 = sqd(I2.x, T2.x) + sqd(I2.y, T2.y);
            float cls = d2f(I2.z, T2.z) + d2f(I2.w, T2.w)
                      + d2f(I3.x, T3.x) + d2f(I3.y, T3.y) + d2f(I3.z, T3.z) + d2f(I3.w, T3.w)
                      + d2f(I4.x, T4.x) + d2f(I4.y, T4.y) + d2f(I4.z, T4.z) + d2f(I4.w, T4.w)
                      + d2f(I5.x, T5.x) + d2f(I5.y, T5.y) + d2f(I5.z, T5.z) + d2f(I5.w, T5.w)
                      + d2f(I6.x, T6.x) + d2f(I6.y, T6.y) + d2f(I6.z, T6.z) + d2f(I6.w, T6.w)
                      + d2f(I7.x, T7.x) + d2f(I7.y, T7.y);
            acc += COORD * (f0 * (xy0 + wh0) + f1 * (xy1 + wh1))
                 + f0 * s0 + f1 * s1
                 + NOOBJ * nf * (s0 + s1)
                 + h * cls;
        }
        // ---- cell B ----
        {
            bool o0 = (T7.z == 1.0f), o1 = (T7.w == 1.0f);
            float f0 = o0 ? 1.0f : 0.0f;
            float f1 = (o1 && !o0) ? 1.0f : 0.0f;
            float nf = (o0 || o1) ? 0.0f : 1.0f;
            float h  = 1.0f - nf;
            float s0 = d2f(I7.z, T7.z), s1 = d2f(I7.w, T7.w);
            float xy0 = d2f(I8.x, T8.x) + d2f(I8.y, T8.y);
            float wh0 = sqd(I8.z, T8.z) + sqd(I8.w, T8.w);
            float xy1 = d2f(I9.x, T9.x) + d2f(I9.y, T9.y);
            float wh1 = sqd(I9.z, T9.z) + sqd(I9.w, T9.w);
            float cls = d2f(I10.x, T10.x) + d2f(I10.y, T10.y) + d2f(I10.z, T10.z) + d2f(I10.w, T10.w)
                      + d2f(I11.x, T11.x) + d2f(I11.y, T11.y) + d2f(I11.z, T11.z) + d2f(I11.w, T11.w)
                      + d2f(I12.x, T12.x) + d2f(I12.y, T12.y) + d2f(I12.z, T12.z) + d2f(I12.w, T12.w)
                      + d2f(I13.x, T13.x) + d2f(I13.y, T13.y) + d2f(I13.z, T13.z) + d2f(I13.w, T13.w)
                      + d2f(I14.x, T14.x) + d2f(I14.y, T14.y) + d2f(I14.z, T14.z) + d2f(I14.w, T14.w);
            acc += COORD * (f0 * (xy0 + wh0) + f1 * (xy1 + wh1))
                 + f0 * s0 + f1 * s1
                 + NOOBJ * nf * (s0 + s1)
                 + h * cls;
        }

        buf ^= 1;
    }

    // ---- wave reduce (block == 1 wave) ----
#pragma unroll
    for (int off = 32; off > 0; off >>= 1)
        acc += __shfl_down(acc, off, 64);
    if (lane == 0) atomicAdd(out, acc * inv_n);
}

extern "C" void kernel_launch(void* const* d_in, const int* in_sizes, int n_in,
                              void* d_out, int out_size, void* d_ws, size_t ws_size,
                              hipStream_t stream) {
    const float* inp = (const float*)d_in[0];
    const float* tgt = (const float*)d_in[1];
    float* out = (float*)d_out;

    hipMemsetAsync(out, 0, sizeof(float), stream);
    yolo_loss_kernel<<<GRID, 64, 0, stream>>>(inp, tgt, out, 1.0f / 4096.0f);
}